// Round 18
// baseline (554.469 us; speedup 1.0000x reference)
//
#include <hip/hip_runtime.h>

#define BATCH 2048
#define CH 512
#define NTOK 49
#define NHEAD 8
#define DHEAD 64

typedef __attribute__((ext_vector_type(8))) short bf16x8;
typedef __attribute__((ext_vector_type(4))) float f32x4;

__device__ __forceinline__ ushort f2bf(float f) {
  union { float f; unsigned u; } v; v.f = f;
  unsigned r = v.u + 0x7fffu + ((v.u >> 16) & 1u);
  return (ushort)(r >> 16);
}

__device__ __forceinline__ float bf2f(ushort u) {
  union { unsigned u; float f; } v; v.u = ((unsigned)u) << 16;
  return v.f;
}

#define MFMA16(a, b, c) __builtin_amdgcn_mfma_f32_16x16x32_bf16((a), (b), (c), 0, 0, 0)

#define GLOAD_LDS16(gsrc, ldst)                                                  \
  __builtin_amdgcn_global_load_lds((const __attribute__((address_space(1))) void*)(gsrc), \
                                   (__attribute__((address_space(3))) void*)(ldst), 16, 0, 0)

// ---------------- Kernel 0: packed weights + fragment-packed bias table ----------------
__global__ void prep_kernel(const float* __restrict__ w_qkv, const float* __restrict__ w_out,
                            const float* __restrict__ rel, ushort* __restrict__ wqkvB,
                            ushort* __restrict__ woutF, float* __restrict__ biasF) {
  int tid = blockIdx.x * blockDim.x + threadIdx.x;
  int stride = gridDim.x * blockDim.x;
  for (int i = tid; i < 12 * 16 * 8 * 64 * 8; i += stride) {
    int j = i & 7, lane = (i >> 3) & 63, cbs = (i >> 9) & 7, kk = (i >> 12) & 15, nb = i >> 16;
    int o = nb * 128 + cbs * 16 + (lane & 15);
    int c = kk * 32 + (lane >> 4) * 8 + j;
    wqkvB[i] = f2bf(w_qkv[c * 1536 + o]);
  }
  for (int i = tid; i < 32 * 16 * 64 * 8; i += stride) {
    int j = i & 7, lane = (i >> 3) & 63, ks = (i >> 9) & 15, cb = i >> 13;
    int o = cb * 16 + (lane & 15);
    int c = ks * 32 + (lane >> 4) * 8 + j;
    woutF[i] = f2bf(w_out[c * 512 + o]);
  }
  for (int i = tid; i < NHEAD * 4 * 4 * 64; i += stride) {
    int lane = i & 63, nt = (i >> 6) & 3, mt = (i >> 8) & 3, h = i >> 10;
    int cc = lane & 15, g = lane >> 4;
    float4 v;
#pragma unroll
    for (int r = 0; r < 4; r++) {
      int n = mt * 16 + 4 * g + r;
      int m = nt * 16 + cc;
      float bv = -1e30f;
      if (n < NTOK && m < NTOK) {
        int dh = n / 7 - m / 7 + 6;
        int dw = n % 7 - m % 7 + 6;
        bv = rel[(dh * 13 + dw) * 8 + h];
      }
      ((float*)&v)[r] = bv;
    }
    ((float4*)biasF)[i] = v;
  }
}

// ---------------- Kernel 1: one-pass LayerNorm, x[b][c][n] f32 -> xn bf16 [b][n][c] ----------------
__global__ __launch_bounds__(256) void ln_kernel(const float* __restrict__ x,
                                                 const float* __restrict__ gamma,
                                                 const float* __restrict__ beta,
                                                 ushort* __restrict__ xnW) {
  int b = blockIdx.x;
  int t = threadIdx.x;
  __shared__ ushort xsb[CH][NTOK];
  __shared__ float muL[64], rsL[64];
  const float4* x4 = (const float4*)(x + (size_t)b * CH * NTOK);
  for (int i4 = t; i4 < CH * NTOK / 4; i4 += 256) {
    float4 v = x4[i4];
    int lf = i4 * 4;
#pragma unroll
    for (int e = 0; e < 4; e++) {
      int idx = lf + e;
      int c = idx / NTOK, n = idx - c * NTOK;
      xsb[c][n] = f2bf(((const float*)&v)[e]);
    }
  }
  __syncthreads();
  int row = t >> 2, sub = t & 3;
  float s = 0.f, s2 = 0.f;
  if (row < NTOK) {
    for (int c = sub; c < CH; c += 4) {
      float v = bf2f(xsb[c][row]);
      s += v;
      s2 += v * v;
    }
  }
  s += __shfl_xor(s, 1);
  s += __shfl_xor(s, 2);
  s2 += __shfl_xor(s2, 1);
  s2 += __shfl_xor(s2, 2);
  if (sub == 0 && row < NTOK) {
    float m = s * (1.f / CH);
    muL[row] = m;
    rsL[row] = rsqrtf(s2 * (1.f / CH) - m * m + 1e-5f);
  }
  __syncthreads();
  ushort* dst = xnW + (size_t)b * NTOK * CH;
  for (int i = t; i < NTOK * 64; i += 256) {
    int n = i >> 6, c0 = (i & 63) * 8;
    float mu = muL[n], rs = rsL[n];
    ushort tmp[8];
#pragma unroll
    for (int j = 0; j < 8; j++) {
      int c = c0 + j;
      tmp[j] = f2bf((bf2f(xsb[c][n]) - mu) * rs * gamma[c] + beta[c]);
    }
    *(uint4*)(dst + (size_t)n * CH + c0) = *(const uint4*)tmp;
  }
}

// ---------------- Kernel 2: QKV GEMM, counted-vmcnt pipeline (order-robust ledger) ----------------
#define QKV_PROLOGUE_STAGE(S)                                                    \
  _Pragma("unroll") for (int i = 0; i < 4; i++)                                  \
      GLOAD_LDS16(xbase + (size_t)(drow + i * 32) * CH + (S) * 64 + gchunk * 8,  \
                  lds + (S) * 8192 + i * 2048 + t * 8);

#define QKV_BLOAD(DST, S)                                                        \
  {                                                                              \
    const ushort* wp_ = wBbase + (size_t)(S) * 8192 + (wn * 4) * 512 + lane * 8; \
    _Pragma("unroll") for (int q_ = 0; q_ < 8; q_++)                             \
        DST[q_] = *(const bf16x8*)(wp_ + (q_ >> 2) * 4096 + (q_ & 3) * 512);     \
  }

#define QKV_STAGE(S, VMC, BCUR, BNXT)                                            \
  {                                                                              \
    asm volatile("s_waitcnt vmcnt(" VMC ")" ::: "memory");                       \
    __builtin_amdgcn_s_barrier();                                                \
    if ((S) + 2 < 8) {                                                           \
      _Pragma("unroll") for (int i = 0; i < 4; i++)                              \
          GLOAD_LDS16(xbase + (size_t)(drow + i * 32) * CH + ((S) + 2) * 64 + gchunk * 8, \
                      lds + (((S) + 2) % 3) * 8192 + i * 2048 + t * 8);          \
    }                                                                            \
    __builtin_amdgcn_sched_barrier(0);                                           \
    if ((S) + 1 < 8) QKV_BLOAD(BNXT, (S) + 1)                                    \
    const ushort* lA_ = lds + ((S) % 3) * 8192;                                  \
    _Pragma("unroll") for (int ks = 0; ks < 2; ks++) {                           \
      bf16x8 afr_[4];                                                            \
      _Pragma("unroll") for (int mt = 0; mt < 4; mt++) {                         \
        int row_ = wm * 64 + mt * 16 + arow;                                     \
        afr_[mt] = *(const bf16x8*)&lA_[row_ * 64 + ((ks * 4 + g) ^ (arow & 7)) * 8]; \
      }                                                                          \
      _Pragma("unroll") for (int mt = 0; mt < 4; mt++)                           \
        _Pragma("unroll") for (int nt = 0; nt < 4; nt++)                         \
            acc[mt][nt] = MFMA16(afr_[mt], BCUR[ks * 4 + nt], acc[mt][nt]);      \
    }                                                                            \
  }

__global__ __launch_bounds__(256, 3) void qkv_gemm(const ushort* __restrict__ xnW,
                                                   const ushort* __restrict__ wqkvB,
                                                   ushort* __restrict__ qW,
                                                   ushort* __restrict__ kW,
                                                   ushort* __restrict__ vW) {
  int bid = blockIdx.x;
  int f = (bid & 7) * 1176 + (bid >> 3);  // bijective XCD swizzle (9408 = 8*1176)
  int mb = f / 12, nb = f - mb * 12;
  int r0 = mb * 128;
  int t = threadIdx.x, lane = t & 63, w = t >> 6;
  int wm = w >> 1, wn = w & 1;

  __shared__ __align__(16) ushort lds[24576];

  const int arow = lane & 15, g = lane >> 4;
  const ushort* wBbase = wqkvB + (size_t)nb * 16 * 4096;
  const ushort* xbase = xnW + (size_t)r0 * CH;

  int drow = t >> 3;
  int slot = t & 7;
  int gchunk = slot ^ (drow & 7);

  f32x4 acc[4][4];
#pragma unroll
  for (int mt = 0; mt < 4; mt++)
#pragma unroll
    for (int nt = 0; nt < 4; nt++) acc[mt][nt] = (f32x4){0.f, 0.f, 0.f, 0.f};

  bf16x8 bA[8], bB[8];
  QKV_PROLOGUE_STAGE(0)
  __builtin_amdgcn_sched_barrier(0);
  QKV_PROLOGUE_STAGE(1)
  QKV_BLOAD(bA, 0)
  // order-robust ledger: S0: gl1(4)+B0(8)=12 | S1..6: gl(S+1)(4)+B(S)(8)=12 | S7: B7(8)=8
  QKV_STAGE(0, "12", bA, bB)
  QKV_STAGE(1, "12", bB, bA)
  QKV_STAGE(2, "12", bA, bB)
  QKV_STAGE(3, "12", bB, bA)
  QKV_STAGE(4, "12", bA, bB)
  QKV_STAGE(5, "12", bB, bA)
  QKV_STAGE(6, "12", bA, bB)
  QKV_STAGE(7, "8", bB, bA)
  __syncthreads();

  ushort(*oL)[136] = (ushort(*)[136])lds;
  int h0 = (nb & 3) * 2;
  int sct = nb >> 2;  // 0=q 1=k 2=v
  float sc = (sct == 0) ? 0.125f : 1.0f;
#pragma unroll
  for (int hh = 0; hh < 2; hh++) {
    if (wm == hh) {
#pragma unroll
      for (int mt = 0; mt < 4; mt++)
#pragma unroll
        for (int nt = 0; nt < 4; nt++)
#pragma unroll
          for (int r = 0; r < 4; r++) {
            int rn = mt * 16 + 4 * g + r;
            oL[rn][wn * 64 + nt * 16 + arow] = f2bf(acc[mt][nt][r] * sc);
          }
    }
    __syncthreads();
    if (sct < 2) {
      ushort* dst = (sct == 0 ? qW : kW);
      for (int i = t; i < 64 * 16; i += 256) {
        int rn = i >> 4, c8 = i & 15;
        int grow = r0 + hh * 64 + rn;
        int b = grow / 49, n = grow - b * 49;
        int h = h0 + (c8 >> 3);
        *(uint4*)(dst + (size_t)(b * 8 + h) * (NTOK * 64) + n * 64 + (c8 & 7) * 8) =
            *(const uint4*)&oL[rn][c8 * 8];
      }
    } else {
      for (int i = t; i < 64 * 128; i += 256) {
        int rn = i & 63, col = i >> 6;
        int grow = r0 + hh * 64 + rn;
        int b = grow / 49, n = grow - b * 49;
        int h = h0 + (col >> 6), d = col & 63;
        vW[(size_t)(b * 8 + h) * 4096 + d * 64 + n] = oL[rn][col];
      }
    }
    __syncthreads();
  }
}

// ---------------- Kernel 3: fused attention + out-proj; P swizzle = XOR + row-rotate ----------------
__global__ __launch_bounds__(512, 3) void attnproj(const ushort* __restrict__ qW,
                                                   const ushort* __restrict__ kW,
                                                   const ushort* __restrict__ vW,
                                                   const float* __restrict__ biasF,
                                                   const ushort* __restrict__ woutF,
                                                   const float* __restrict__ b_out,
                                                   const float* __restrict__ x,
                                                   float* __restrict__ out) {
  int b = blockIdx.x;
  int t = threadIdx.x;
  int lane = t & 63;
  int w = t >> 6;

  // union: P 8x[49][64] (50176B) -> aoL us[49][520] (50960B) -> oL f32[49][261] (51156B)
  __shared__ __align__(16) ushort lds[25578];
  ushort* plb = lds + w * 3136;

  const int c = lane & 15, g = lane >> 4;
  const ushort* qb = qW + (size_t)(b * 8 + w) * NTOK * 64;
  const ushort* kb = kW + (size_t)(b * 8 + w) * NTOK * 64;
  const ushort* vb = vW + (size_t)(b * 8 + w) * 64 * 64;
  const float4* bf = (const float4*)biasF + (size_t)w * 16 * 64;

  f32x4 s[4][4];
#pragma unroll
  for (int mt = 0; mt < 4; mt++)
#pragma unroll
    for (int nt = 0; nt < 4; nt++) s[mt][nt] = (f32x4){0.f, 0.f, 0.f, 0.f};
  __builtin_amdgcn_s_setprio(1);
#pragma unroll
  for (int ks = 0; ks < 2; ks++) {
    bf16x8 kf[4];
#pragma unroll
    for (int nt = 0; nt < 4; nt++)
      kf[nt] = *(const bf16x8*)(kb + (size_t)(nt * 16 + c) * 64 + ks * 32 + g * 8);
#pragma unroll
    for (int mt = 0; mt < 4; mt++) {
      bf16x8 qf = *(const bf16x8*)(qb + (size_t)(mt * 16 + c) * 64 + ks * 32 + g * 8);
#pragma unroll
      for (int nt = 0; nt < 4; nt++) s[mt][nt] = MFMA16(qf, kf[nt], s[mt][nt]);
    }
  }
  __builtin_amdgcn_s_setprio(0);

#pragma unroll
  for (int mt = 0; mt < 4; mt++)
#pragma unroll
    for (int nt = 0; nt < 4; nt++) {
      float4 bb = bf[(mt * 4 + nt) * 64 + lane];
#pragma unroll
      for (int r = 0; r < 4; r++) s[mt][nt][r] += ((const float*)&bb)[r];
    }

  // ---- softmax -> P to LDS; phys chunk = ((logical ^ (n&7)) + (n>>3)) & 7 ----
#pragma unroll
  for (int mt = 0; mt < 4; mt++)
#pragma unroll
    for (int r = 0; r < 4; r++) {
      float mx = fmaxf(fmaxf(s[mt][0][r], s[mt][1][r]), fmaxf(s[mt][2][r], s[mt][3][r]));
      mx = fmaxf(mx, __shfl_xor(mx, 1));
      mx = fmaxf(mx, __shfl_xor(mx, 2));
      mx = fmaxf(mx, __shfl_xor(mx, 4));
      mx = fmaxf(mx, __shfl_xor(mx, 8));
      float p0 = __expf(s[mt][0][r] - mx);
      float p1 = __expf(s[mt][1][r] - mx);
      float p2 = __expf(s[mt][2][r] - mx);
      float p3 = __expf(s[mt][3][r] - mx);
      float sum = p0 + p1 + p2 + p3;
      sum += __shfl_xor(sum, 1);
      sum += __shfl_xor(sum, 2);
      sum += __shfl_xor(sum, 4);
      sum += __shfl_xor(sum, 8);
      float rinv = 1.f / sum;
      int n = mt * 16 + 4 * g + r;
      if (n < NTOK) {
        int n7 = n & 7, rot = n >> 3;
        int chi = c >> 3, clo = c & 7;
        plb[n * 64 + ((((0 + chi) ^ n7) + rot) & 7) * 8 + clo] = f2bf(p0 * rinv);
        plb[n * 64 + ((((2 + chi) ^ n7) + rot) & 7) * 8 + clo] = f2bf(p1 * rinv);
        plb[n * 64 + ((((4 + chi) ^ n7) + rot) & 7) * 8 + clo] = f2bf(p2 * rinv);
        plb[n * 64 + ((((6 + chi) ^ n7) + rot) & 7) * 8 + clo] = f2bf(p3 * rinv);
      }
    }

  // ---- O = P V (A rows clamped to 48; output rows >=49 garbage, discarded) ----
  f32x4 o[4][4];
#pragma unroll
  for (int mt = 0; mt < 4; mt++)
#pragma unroll
    for (int nt = 0; nt < 4; nt++) o[mt][nt] = (f32x4){0.f, 0.f, 0.f, 0.f};
  __builtin_amdgcn_s_setprio(1);
#pragma unroll
  for (int ks = 0; ks < 2; ks++) {
    bf16x8 vf[4];
#pragma unroll
    for (int nt = 0; nt < 4; nt++)
      vf[nt] = *(const bf16x8*)(vb + (size_t)(nt * 16 + c) * 64 + ks * 32 + g * 8);
#pragma unroll
    for (int mt = 0; mt < 4; mt++) {
      int row = mt * 16 + c;
      int rr = row < NTOK ? row : 48;
      bf16x8 pf = *(const bf16x8*)&plb[rr * 64 + ((((ks * 4 + g) ^ (rr & 7)) + (rr >> 3)) & 7) * 8];
#pragma unroll
      for (int nt = 0; nt < 4; nt++) o[mt][nt] = MFMA16(pf, vf[nt], o[mt][nt]);
    }
  }
  __builtin_amdgcn_s_setprio(0);

  bf16x8 bcur[4];
#pragma unroll
  for (int nt = 0; nt < 4; nt++)
    bcur[nt] = *(const bf16x8*)(woutF + ((size_t)((w * 4 + nt) * 16 + 0)) * 512 + lane * 8);

  __syncthreads();

  ushort(*aoL)[520] = (ushort(*)[520])lds;
#pragma unroll
  for (int mt = 0; mt < 4; mt++)
#pragma unroll
    for (int nt = 0; nt < 4; nt++)
#pragma unroll
      for (int r = 0; r < 4; r++) {
        int n = mt * 16 + 4 * g + r;
        if (n < NTOK) aoL[n][w * 64 + nt * 16 + c] = f2bf(o[mt][nt][r]);
      }
  __syncthreads();

  f32x4 pacc[4][4];
#pragma unroll
  for (int mt = 0; mt < 4; mt++)
#pragma unroll
    for (int nt = 0; nt < 4; nt++) pacc[mt][nt] = (f32x4){0.f, 0.f, 0.f, 0.f};
#pragma unroll
  for (int step = 0; step < 16; step++) {
    bf16x8 bnxt[4];
    if (step < 15) {
#pragma unroll
      for (int nt = 0; nt < 4; nt++)
        bnxt[nt] = *(const bf16x8*)(woutF + ((size_t)((w * 4 + nt) * 16 + step + 1)) * 512 + lane * 8);
    }
    bf16x8 afr[4];
#pragma unroll
    for (int mt = 0; mt < 4; mt++) {
      int row = mt * 16 + c;
      int rr = row < NTOK ? row : 48;
      afr[mt] = *(const bf16x8*)&aoL[rr][step * 32 + g * 8];
    }
    __builtin_amdgcn_s_setprio(1);
#pragma unroll
    for (int mt = 0; mt < 4; mt++)
#pragma unroll
      for (int nt = 0; nt < 4; nt++) pacc[mt][nt] = MFMA16(afr[mt], bcur[nt], pacc[mt][nt]);
    __builtin_amdgcn_s_setprio(0);
#pragma unroll
    for (int nt = 0; nt < 4; nt++) bcur[nt] = bnxt[nt];
  }

  float(*oL)[261] = (float(*)[261])lds;  // 261 dwords/row: banks rotate 5/row, g-groups distinct
  for (int half = 0; half < 2; half++) {
    __syncthreads();
    if ((w >> 2) == half) {
      int wl = w & 3;
#pragma unroll
      for (int mt = 0; mt < 4; mt++)
#pragma unroll
        for (int nt = 0; nt < 4; nt++)
#pragma unroll
          for (int r = 0; r < 4; r++) {
            int rn = mt * 16 + 4 * g + r;
            if (rn < NTOK) oL[rn][wl * 64 + nt * 16 + c] = pacc[mt][nt][r];
          }
    }
    __syncthreads();
    int c0 = half * 256;
    const float4* x4 = (const float4*)(x + ((size_t)b * CH + c0) * NTOK);
    float4* o4 = (float4*)(out + ((size_t)b * CH + c0) * NTOK);
    const float* bo = b_out + c0;
    for (int i = t; i < 3136; i += 512) {
      float4 xv = x4[i];
      float4 ov;
      int lf = i * 4;
#pragma unroll
      for (int e = 0; e < 4; e++) {
        int cl = (lf + e) / NTOK, n = (lf + e) - cl * NTOK;
        ((float*)&ov)[e] = oL[n][cl] + bo[cl] + ((const float*)&xv)[e];
      }
      o4[i] = ov;
    }
  }
}

extern "C" void kernel_launch(void* const* d_in, const int* in_sizes, int n_in,
                              void* d_out, int out_size, void* d_ws, size_t ws_size,
                              hipStream_t stream) {
  const float* x = (const float*)d_in[0];
  const float* gamma = (const float*)d_in[1];
  const float* beta = (const float*)d_in[2];
  const float* w_qkv = (const float*)d_in[3];
  const float* rel = (const float*)d_in[4];
  const float* w_out = (const float*)d_in[5];
  const float* b_out = (const float*)d_in[6];
  float* out = (float*)d_out;

  char* ws = (char*)d_ws;
  size_t off = 0;
  ushort* wqkvB = (ushort*)(ws + off); off += (size_t)12 * 16 * 4096 * 2;
  ushort* woutF = (ushort*)(ws + off); off += (size_t)512 * 512 * 2;
  float* biasF = (float*)(ws + off);   off += (size_t)NHEAD * 16 * 64 * 4 * 4;  // 128 KB
  ushort* qW = (ushort*)(ws + off);    off += ((size_t)BATCH * 8 * NTOK * 64 + 1024) * 2;
  ushort* kW = (ushort*)(ws + off);    off += ((size_t)BATCH * 8 * NTOK * 64 + 1024) * 2;
  ushort* vW = (ushort*)(ws + off);    off += (size_t)BATCH * 8 * 64 * 64 * 2;
  ushort* xnW = (ushort*)(ws + off);   off += (size_t)BATCH * NTOK * CH * 2;
  (void)ws_size;

  prep_kernel<<<1024, 256, 0, stream>>>(w_qkv, w_out, rel, wqkvB, woutF, biasF);
  ln_kernel<<<BATCH, 256, 0, stream>>>(x, gamma, beta, xnW);
  qkv_gemm<<<784 * 12, 256, 0, stream>>>(xnW, wqkvB, qW, kW, vW);
  attnproj<<<BATCH, 512, 0, stream>>>(qW, kW, vW, biasF, woutF, b_out, x, out);
}

// Round 19
// 550.903 us; speedup vs baseline: 1.0065x; 1.0065x over previous
//
#include <hip/hip_runtime.h>

#define BATCH 2048
#define CH 512
#define NTOK 49
#define NHEAD 8
#define DHEAD 64

typedef __attribute__((ext_vector_type(8))) short bf16x8;
typedef __attribute__((ext_vector_type(4))) float f32x4;

__device__ __forceinline__ ushort f2bf(float f) {
  union { float f; unsigned u; } v; v.f = f;
  unsigned r = v.u + 0x7fffu + ((v.u >> 16) & 1u);
  return (ushort)(r >> 16);
}

__device__ __forceinline__ float bf2f(ushort u) {
  union { unsigned u; float f; } v; v.u = ((unsigned)u) << 16;
  return v.f;
}

#define MFMA16(a, b, c) __builtin_amdgcn_mfma_f32_16x16x32_bf16((a), (b), (c), 0, 0, 0)

#define GLOAD_LDS16(gsrc, ldst)                                                  \
  __builtin_amdgcn_global_load_lds((const __attribute__((address_space(1))) void*)(gsrc), \
                                   (__attribute__((address_space(3))) void*)(ldst), 16, 0, 0)

// ---------------- Kernel 0: packed weights + fragment-packed bias table ----------------
__global__ void prep_kernel(const float* __restrict__ w_qkv, const float* __restrict__ w_out,
                            const float* __restrict__ rel, ushort* __restrict__ wqkvB,
                            ushort* __restrict__ woutF, float* __restrict__ biasF) {
  int tid = blockIdx.x * blockDim.x + threadIdx.x;
  int stride = gridDim.x * blockDim.x;
  for (int i = tid; i < 12 * 16 * 8 * 64 * 8; i += stride) {
    int j = i & 7, lane = (i >> 3) & 63, cbs = (i >> 9) & 7, kk = (i >> 12) & 15, nb = i >> 16;
    int o = nb * 128 + cbs * 16 + (lane & 15);
    int c = kk * 32 + (lane >> 4) * 8 + j;
    wqkvB[i] = f2bf(w_qkv[c * 1536 + o]);
  }
  for (int i = tid; i < 32 * 16 * 64 * 8; i += stride) {
    int j = i & 7, lane = (i >> 3) & 63, ks = (i >> 9) & 15, cb = i >> 13;
    int o = cb * 16 + (lane & 15);
    int c = ks * 32 + (lane >> 4) * 8 + j;
    woutF[i] = f2bf(w_out[c * 512 + o]);
  }
  for (int i = tid; i < NHEAD * 4 * 4 * 64; i += stride) {
    int lane = i & 63, nt = (i >> 6) & 3, mt = (i >> 8) & 3, h = i >> 10;
    int cc = lane & 15, g = lane >> 4;
    float4 v;
#pragma unroll
    for (int r = 0; r < 4; r++) {
      int n = mt * 16 + 4 * g + r;
      int m = nt * 16 + cc;
      float bv = -1e30f;
      if (n < NTOK && m < NTOK) {
        int dh = n / 7 - m / 7 + 6;
        int dw = n % 7 - m % 7 + 6;
        bv = rel[(dh * 13 + dw) * 8 + h];
      }
      ((float*)&v)[r] = bv;
    }
    ((float4*)biasF)[i] = v;
  }
}

// ---------------- Kernel 1: one-pass LayerNorm, x[b][c][n] f32 -> xn bf16 [b][n][c] ----------------
__global__ __launch_bounds__(256) void ln_kernel(const float* __restrict__ x,
                                                 const float* __restrict__ gamma,
                                                 const float* __restrict__ beta,
                                                 ushort* __restrict__ xnW) {
  int b = blockIdx.x;
  int t = threadIdx.x;
  __shared__ ushort xsb[CH][NTOK];
  __shared__ float muL[64], rsL[64];
  const float4* x4 = (const float4*)(x + (size_t)b * CH * NTOK);
  for (int i4 = t; i4 < CH * NTOK / 4; i4 += 256) {
    float4 v = x4[i4];
    int lf = i4 * 4;
#pragma unroll
    for (int e = 0; e < 4; e++) {
      int idx = lf + e;
      int c = idx / NTOK, n = idx - c * NTOK;
      xsb[c][n] = f2bf(((const float*)&v)[e]);
    }
  }
  __syncthreads();
  int row = t >> 2, sub = t & 3;
  float s = 0.f, s2 = 0.f;
  if (row < NTOK) {
    for (int c = sub; c < CH; c += 4) {
      float v = bf2f(xsb[c][row]);
      s += v;
      s2 += v * v;
    }
  }
  s += __shfl_xor(s, 1);
  s += __shfl_xor(s, 2);
  s2 += __shfl_xor(s2, 1);
  s2 += __shfl_xor(s2, 2);
  if (sub == 0 && row < NTOK) {
    float m = s * (1.f / CH);
    muL[row] = m;
    rsL[row] = rsqrtf(s2 * (1.f / CH) - m * m + 1e-5f);
  }
  __syncthreads();
  ushort* dst = xnW + (size_t)b * NTOK * CH;
  for (int i = t; i < NTOK * 64; i += 256) {
    int n = i >> 6, c0 = (i & 63) * 8;
    float mu = muL[n], rs = rsL[n];
    ushort tmp[8];
#pragma unroll
    for (int j = 0; j < 8; j++) {
      int c = c0 + j;
      tmp[j] = f2bf((bf2f(xsb[c][n]) - mu) * rs * gamma[c] + beta[c]);
    }
    *(uint4*)(dst + (size_t)n * CH + c0) = *(const uint4*)tmp;
  }
}

// ---------------- Kernel 2: QKV GEMM, counted-vmcnt pipeline (order-robust ledger) ----------------
#define QKV_PROLOGUE_STAGE(S)                                                    \
  _Pragma("unroll") for (int i = 0; i < 4; i++)                                  \
      GLOAD_LDS16(xbase + (size_t)(drow + i * 32) * CH + (S) * 64 + gchunk * 8,  \
                  lds + (S) * 8192 + i * 2048 + t * 8);

#define QKV_BLOAD(DST, S)                                                        \
  {                                                                              \
    const ushort* wp_ = wBbase + (size_t)(S) * 8192 + (wn * 4) * 512 + lane * 8; \
    _Pragma("unroll") for (int q_ = 0; q_ < 8; q_++)                             \
        DST[q_] = *(const bf16x8*)(wp_ + (q_ >> 2) * 4096 + (q_ & 3) * 512);     \
  }

#define QKV_STAGE(S, VMC, BCUR, BNXT)                                            \
  {                                                                              \
    asm volatile("s_waitcnt vmcnt(" VMC ")" ::: "memory");                       \
    __builtin_amdgcn_s_barrier();                                                \
    if ((S) + 2 < 8) {                                                           \
      _Pragma("unroll") for (int i = 0; i < 4; i++)                              \
          GLOAD_LDS16(xbase + (size_t)(drow + i * 32) * CH + ((S) + 2) * 64 + gchunk * 8, \
                      lds + (((S) + 2) % 3) * 8192 + i * 2048 + t * 8);          \
    }                                                                            \
    __builtin_amdgcn_sched_barrier(0);                                           \
    if ((S) + 1 < 8) QKV_BLOAD(BNXT, (S) + 1)                                    \
    const ushort* lA_ = lds + ((S) % 3) * 8192;                                  \
    _Pragma("unroll") for (int ks = 0; ks < 2; ks++) {                           \
      bf16x8 afr_[4];                                                            \
      _Pragma("unroll") for (int mt = 0; mt < 4; mt++) {                         \
        int row_ = wm * 64 + mt * 16 + arow;                                     \
        afr_[mt] = *(const bf16x8*)&lA_[row_ * 64 + ((ks * 4 + g) ^ (arow & 7)) * 8]; \
      }                                                                          \
      _Pragma("unroll") for (int mt = 0; mt < 4; mt++)                           \
        _Pragma("unroll") for (int nt = 0; nt < 4; nt++)                         \
            acc[mt][nt] = MFMA16(afr_[mt], BCUR[ks * 4 + nt], acc[mt][nt]);      \
    }                                                                            \
  }

__global__ __launch_bounds__(256, 3) void qkv_gemm(const ushort* __restrict__ xnW,
                                                   const ushort* __restrict__ wqkvB,
                                                   ushort* __restrict__ qW,
                                                   ushort* __restrict__ kW,
                                                   ushort* __restrict__ vW) {
  int bid = blockIdx.x;
  int f = (bid & 7) * 1176 + (bid >> 3);  // bijective XCD swizzle (9408 = 8*1176)
  int mb = f / 12, nb = f - mb * 12;
  int r0 = mb * 128;
  int t = threadIdx.x, lane = t & 63, w = t >> 6;
  int wm = w >> 1, wn = w & 1;

  __shared__ __align__(16) ushort lds[24576];

  const int arow = lane & 15, g = lane >> 4;
  const ushort* wBbase = wqkvB + (size_t)nb * 16 * 4096;
  const ushort* xbase = xnW + (size_t)r0 * CH;

  int drow = t >> 3;
  int slot = t & 7;
  int gchunk = slot ^ (drow & 7);

  f32x4 acc[4][4];
#pragma unroll
  for (int mt = 0; mt < 4; mt++)
#pragma unroll
    for (int nt = 0; nt < 4; nt++) acc[mt][nt] = (f32x4){0.f, 0.f, 0.f, 0.f};

  bf16x8 bA[8], bB[8];
  QKV_PROLOGUE_STAGE(0)
  __builtin_amdgcn_sched_barrier(0);
  QKV_PROLOGUE_STAGE(1)
  QKV_BLOAD(bA, 0)
  // order-robust ledger: S0: gl1(4)+B0(8)=12 | S1..6: gl(S+1)(4)+B(S)(8)=12 | S7: B7(8)=8
  QKV_STAGE(0, "12", bA, bB)
  QKV_STAGE(1, "12", bB, bA)
  QKV_STAGE(2, "12", bA, bB)
  QKV_STAGE(3, "12", bB, bA)
  QKV_STAGE(4, "12", bA, bB)
  QKV_STAGE(5, "12", bB, bA)
  QKV_STAGE(6, "12", bA, bB)
  QKV_STAGE(7, "8", bB, bA)
  __syncthreads();

  ushort(*oL)[136] = (ushort(*)[136])lds;
  int h0 = (nb & 3) * 2;
  int sct = nb >> 2;  // 0=q 1=k 2=v
  float sc = (sct == 0) ? 0.125f : 1.0f;
#pragma unroll
  for (int hh = 0; hh < 2; hh++) {
    if (wm == hh) {
#pragma unroll
      for (int mt = 0; mt < 4; mt++)
#pragma unroll
        for (int nt = 0; nt < 4; nt++)
#pragma unroll
          for (int r = 0; r < 4; r++) {
            int rn = mt * 16 + 4 * g + r;
            oL[rn][wn * 64 + nt * 16 + arow] = f2bf(acc[mt][nt][r] * sc);
          }
    }
    __syncthreads();
    if (sct < 2) {
      ushort* dst = (sct == 0 ? qW : kW);
      for (int i = t; i < 64 * 16; i += 256) {
        int rn = i >> 4, c8 = i & 15;
        int grow = r0 + hh * 64 + rn;
        int b = grow / 49, n = grow - b * 49;
        int h = h0 + (c8 >> 3);
        *(uint4*)(dst + (size_t)(b * 8 + h) * (NTOK * 64) + n * 64 + (c8 & 7) * 8) =
            *(const uint4*)&oL[rn][c8 * 8];
      }
    } else {
      for (int i = t; i < 64 * 128; i += 256) {
        int rn = i & 63, col = i >> 6;
        int grow = r0 + hh * 64 + rn;
        int b = grow / 49, n = grow - b * 49;
        int h = h0 + (col >> 6), d = col & 63;
        vW[(size_t)(b * 8 + h) * 4096 + d * 64 + n] = oL[rn][col];
      }
    }
    __syncthreads();
  }
}

// ---------------- Kernel 3: fused attention + out-proj (R17-proven best) ----------------
__global__ __launch_bounds__(512, 3) void attnproj(const ushort* __restrict__ qW,
                                                   const ushort* __restrict__ kW,
                                                   const ushort* __restrict__ vW,
                                                   const float* __restrict__ biasF,
                                                   const ushort* __restrict__ woutF,
                                                   const float* __restrict__ b_out,
                                                   const float* __restrict__ x,
                                                   float* __restrict__ out) {
  int b = blockIdx.x;
  int t = threadIdx.x;
  int lane = t & 63;
  int w = t >> 6;

  __shared__ __align__(16) ushort lds[25480];
  ushort* plb = lds + w * 3136;

  const int c = lane & 15, g = lane >> 4;
  const ushort* qb = qW + (size_t)(b * 8 + w) * NTOK * 64;
  const ushort* kb = kW + (size_t)(b * 8 + w) * NTOK * 64;
  const ushort* vb = vW + (size_t)(b * 8 + w) * 64 * 64;
  const float4* bf = (const float4*)biasF + (size_t)w * 16 * 64;

  f32x4 s[4][4];
#pragma unroll
  for (int mt = 0; mt < 4; mt++)
#pragma unroll
    for (int nt = 0; nt < 4; nt++) s[mt][nt] = (f32x4){0.f, 0.f, 0.f, 0.f};
  __builtin_amdgcn_s_setprio(1);
#pragma unroll
  for (int ks = 0; ks < 2; ks++) {
    bf16x8 kf[4];
#pragma unroll
    for (int nt = 0; nt < 4; nt++)
      kf[nt] = *(const bf16x8*)(kb + (size_t)(nt * 16 + c) * 64 + ks * 32 + g * 8);
#pragma unroll
    for (int mt = 0; mt < 4; mt++) {
      bf16x8 qf = *(const bf16x8*)(qb + (size_t)(mt * 16 + c) * 64 + ks * 32 + g * 8);
#pragma unroll
      for (int nt = 0; nt < 4; nt++) s[mt][nt] = MFMA16(qf, kf[nt], s[mt][nt]);
    }
  }
  __builtin_amdgcn_s_setprio(0);

#pragma unroll
  for (int mt = 0; mt < 4; mt++)
#pragma unroll
    for (int nt = 0; nt < 4; nt++) {
      float4 bb = bf[(mt * 4 + nt) * 64 + lane];
#pragma unroll
      for (int r = 0; r < 4; r++) s[mt][nt][r] += ((const float*)&bb)[r];
    }

#pragma unroll
  for (int mt = 0; mt < 4; mt++)
#pragma unroll
    for (int r = 0; r < 4; r++) {
      float mx = fmaxf(fmaxf(s[mt][0][r], s[mt][1][r]), fmaxf(s[mt][2][r], s[mt][3][r]));
      mx = fmaxf(mx, __shfl_xor(mx, 1));
      mx = fmaxf(mx, __shfl_xor(mx, 2));
      mx = fmaxf(mx, __shfl_xor(mx, 4));
      mx = fmaxf(mx, __shfl_xor(mx, 8));
      float p0 = __expf(s[mt][0][r] - mx);
      float p1 = __expf(s[mt][1][r] - mx);
      float p2 = __expf(s[mt][2][r] - mx);
      float p3 = __expf(s[mt][3][r] - mx);
      float sum = p0 + p1 + p2 + p3;
      sum += __shfl_xor(sum, 1);
      sum += __shfl_xor(sum, 2);
      sum += __shfl_xor(sum, 4);
      sum += __shfl_xor(sum, 8);
      float rinv = 1.f / sum;
      int n = mt * 16 + 4 * g + r;
      if (n < NTOK) {
        int n7 = n & 7;
        int chi = c >> 3, clo = c & 7;
        plb[n * 64 + ((0 + chi) ^ n7) * 8 + clo] = f2bf(p0 * rinv);
        plb[n * 64 + ((2 + chi) ^ n7) * 8 + clo] = f2bf(p1 * rinv);
        plb[n * 64 + ((4 + chi) ^ n7) * 8 + clo] = f2bf(p2 * rinv);
        plb[n * 64 + ((6 + chi) ^ n7) * 8 + clo] = f2bf(p3 * rinv);
      }
    }

  f32x4 o[4][4];
#pragma unroll
  for (int mt = 0; mt < 4; mt++)
#pragma unroll
    for (int nt = 0; nt < 4; nt++) o[mt][nt] = (f32x4){0.f, 0.f, 0.f, 0.f};
  __builtin_amdgcn_s_setprio(1);
#pragma unroll
  for (int ks = 0; ks < 2; ks++) {
    bf16x8 vf[4];
#pragma unroll
    for (int nt = 0; nt < 4; nt++)
      vf[nt] = *(const bf16x8*)(vb + (size_t)(nt * 16 + c) * 64 + ks * 32 + g * 8);
#pragma unroll
    for (int mt = 0; mt < 4; mt++) {
      int row = mt * 16 + c;
      int rr = row < NTOK ? row : 48;
      bf16x8 pf = *(const bf16x8*)&plb[rr * 64 + ((ks * 4 + g) ^ (rr & 7)) * 8];
#pragma unroll
      for (int nt = 0; nt < 4; nt++) o[mt][nt] = MFMA16(pf, vf[nt], o[mt][nt]);
    }
  }
  __builtin_amdgcn_s_setprio(0);

  bf16x8 bcur[4];
#pragma unroll
  for (int nt = 0; nt < 4; nt++)
    bcur[nt] = *(const bf16x8*)(woutF + ((size_t)((w * 4 + nt) * 16 + 0)) * 512 + lane * 8);

  __syncthreads();

  ushort(*aoL)[520] = (ushort(*)[520])lds;
#pragma unroll
  for (int mt = 0; mt < 4; mt++)
#pragma unroll
    for (int nt = 0; nt < 4; nt++)
#pragma unroll
      for (int r = 0; r < 4; r++) {
        int n = mt * 16 + 4 * g + r;
        if (n < NTOK) aoL[n][w * 64 + nt * 16 + c] = f2bf(o[mt][nt][r]);
      }
  __syncthreads();

  f32x4 pacc[4][4];
#pragma unroll
  for (int mt = 0; mt < 4; mt++)
#pragma unroll
    for (int nt = 0; nt < 4; nt++) pacc[mt][nt] = (f32x4){0.f, 0.f, 0.f, 0.f};
#pragma unroll
  for (int step = 0; step < 16; step++) {
    bf16x8 bnxt[4];
    if (step < 15) {
#pragma unroll
      for (int nt = 0; nt < 4; nt++)
        bnxt[nt] = *(const bf16x8*)(woutF + ((size_t)((w * 4 + nt) * 16 + step + 1)) * 512 + lane * 8);
    }
    bf16x8 afr[4];
#pragma unroll
    for (int mt = 0; mt < 4; mt++) {
      int row = mt * 16 + c;
      int rr = row < NTOK ? row : 48;
      afr[mt] = *(const bf16x8*)&aoL[rr][step * 32 + g * 8];
    }
    __builtin_amdgcn_s_setprio(1);
#pragma unroll
    for (int mt = 0; mt < 4; mt++)
#pragma unroll
      for (int nt = 0; nt < 4; nt++) pacc[mt][nt] = MFMA16(afr[mt], bcur[nt], pacc[mt][nt]);
    __builtin_amdgcn_s_setprio(0);
#pragma unroll
    for (int nt = 0; nt < 4; nt++) bcur[nt] = bnxt[nt];
  }

  float(*oL)[260] = (float(*)[260])lds;
  for (int half = 0; half < 2; half++) {
    __syncthreads();
    if ((w >> 2) == half) {
      int wl = w & 3;
#pragma unroll
      for (int mt = 0; mt < 4; mt++)
#pragma unroll
        for (int nt = 0; nt < 4; nt++)
#pragma unroll
          for (int r = 0; r < 4; r++) {
            int rn = mt * 16 + 4 * g + r;
            if (rn < NTOK) oL[rn][wl * 64 + nt * 16 + c] = pacc[mt][nt][r];
          }
    }
    __syncthreads();
    int c0 = half * 256;
    const float4* x4 = (const float4*)(x + ((size_t)b * CH + c0) * NTOK);
    float4* o4 = (float4*)(out + ((size_t)b * CH + c0) * NTOK);
    const float* bo = b_out + c0;
    for (int i = t; i < 3136; i += 512) {
      float4 xv = x4[i];
      float4 ov;
      int lf = i * 4;
#pragma unroll
      for (int e = 0; e < 4; e++) {
        int cl = (lf + e) / NTOK, n = (lf + e) - cl * NTOK;
        ((float*)&ov)[e] = oL[n][cl] + bo[cl] + ((const float*)&xv)[e];
      }
      o4[i] = ov;
    }
  }
}

extern "C" void kernel_launch(void* const* d_in, const int* in_sizes, int n_in,
                              void* d_out, int out_size, void* d_ws, size_t ws_size,
                              hipStream_t stream) {
  const float* x = (const float*)d_in[0];
  const float* gamma = (const float*)d_in[1];
  const float* beta = (const float*)d_in[2];
  const float* w_qkv = (const float*)d_in[3];
  const float* rel = (const float*)d_in[4];
  const float* w_out = (const float*)d_in[5];
  const float* b_out = (const float*)d_in[6];
  float* out = (float*)d_out;

  char* ws = (char*)d_ws;
  size_t off = 0;
  ushort* wqkvB = (ushort*)(ws + off); off += (size_t)12 * 16 * 4096 * 2;
  ushort* woutF = (ushort*)(ws + off); off += (size_t)512 * 512 * 2;
  float* biasF = (float*)(ws + off);   off += (size_t)NHEAD * 16 * 64 * 4 * 4;  // 128 KB
  ushort* qW = (ushort*)(ws + off);    off += ((size_t)BATCH * 8 * NTOK * 64 + 1024) * 2;
  ushort* kW = (ushort*)(ws + off);    off += ((size_t)BATCH * 8 * NTOK * 64 + 1024) * 2;
  ushort* vW = (ushort*)(ws + off);    off += (size_t)BATCH * 8 * 64 * 64 * 2;
  ushort* xnW = (ushort*)(ws + off);   off += (size_t)BATCH * NTOK * CH * 2;
  (void)ws_size;

  prep_kernel<<<1024, 256, 0, stream>>>(w_qkv, w_out, rel, wqkvB, woutF, biasF);
  ln_kernel<<<BATCH, 256, 0, stream>>>(x, gamma, beta, xnW);
  qkv_gemm<<<784 * 12, 256, 0, stream>>>(xnW, wqkvB, qW, kW, vW);
  attnproj<<<BATCH, 512, 0, stream>>>(qW, kW, vW, biasF, woutF, b_out, x, out);
}

// Round 20
// 545.739 us; speedup vs baseline: 1.0160x; 1.0095x over previous
//
#include <hip/hip_runtime.h>

#define BATCH 2048
#define CH 512
#define NTOK 49
#define NHEAD 8
#define DHEAD 64

typedef __attribute__((ext_vector_type(8))) short bf16x8;
typedef __attribute__((ext_vector_type(4))) float f32x4;

__device__ __forceinline__ ushort f2bf(float f) {
  union { float f; unsigned u; } v; v.f = f;
  unsigned r = v.u + 0x7fffu + ((v.u >> 16) & 1u);
  return (ushort)(r >> 16);
}

__device__ __forceinline__ float bf2f(ushort u) {
  union { unsigned u; float f; } v; v.u = ((unsigned)u) << 16;
  return v.f;
}

#define MFMA16(a, b, c) __builtin_amdgcn_mfma_f32_16x16x32_bf16((a), (b), (c), 0, 0, 0)

#define GLOAD_LDS16(gsrc, ldst)                                                  \
  __builtin_amdgcn_global_load_lds((const __attribute__((address_space(1))) void*)(gsrc), \
                                   (__attribute__((address_space(3))) void*)(ldst), 16, 0, 0)

// ---------------- Kernel 0: packed weights + fragment-packed bias table ----------------
__global__ void prep_kernel(const float* __restrict__ w_qkv, const float* __restrict__ w_out,
                            const float* __restrict__ rel, ushort* __restrict__ wqkvB,
                            ushort* __restrict__ woutF, float* __restrict__ biasF) {
  int tid = blockIdx.x * blockDim.x + threadIdx.x;
  int stride = gridDim.x * blockDim.x;
  for (int i = tid; i < 12 * 16 * 8 * 64 * 8; i += stride) {
    int j = i & 7, lane = (i >> 3) & 63, cbs = (i >> 9) & 7, kk = (i >> 12) & 15, nb = i >> 16;
    int o = nb * 128 + cbs * 16 + (lane & 15);
    int c = kk * 32 + (lane >> 4) * 8 + j;
    wqkvB[i] = f2bf(w_qkv[c * 1536 + o]);
  }
  for (int i = tid; i < 32 * 16 * 64 * 8; i += stride) {
    int j = i & 7, lane = (i >> 3) & 63, ks = (i >> 9) & 15, cb = i >> 13;
    int o = cb * 16 + (lane & 15);
    int c = ks * 32 + (lane >> 4) * 8 + j;
    woutF[i] = f2bf(w_out[c * 512 + o]);
  }
  for (int i = tid; i < NHEAD * 4 * 4 * 64; i += stride) {
    int lane = i & 63, nt = (i >> 6) & 3, mt = (i >> 8) & 3, h = i >> 10;
    int cc = lane & 15, g = lane >> 4;
    float4 v;
#pragma unroll
    for (int r = 0; r < 4; r++) {
      int n = mt * 16 + 4 * g + r;
      int m = nt * 16 + cc;
      float bv = -1e30f;
      if (n < NTOK && m < NTOK) {
        int dh = n / 7 - m / 7 + 6;
        int dw = n % 7 - m % 7 + 6;
        bv = rel[(dh * 13 + dw) * 8 + h];
      }
      ((float*)&v)[r] = bv;
    }
    ((float4*)biasF)[i] = v;
  }
}

// ---------------- Kernel 1: one-pass LayerNorm, x[b][c][n] f32 -> xn bf16 [b][n][c] ----------------
__global__ __launch_bounds__(256) void ln_kernel(const float* __restrict__ x,
                                                 const float* __restrict__ gamma,
                                                 const float* __restrict__ beta,
                                                 ushort* __restrict__ xnW) {
  int b = blockIdx.x;
  int t = threadIdx.x;
  __shared__ ushort xsb[CH][NTOK];
  __shared__ float muL[64], rsL[64];
  const float4* x4 = (const float4*)(x + (size_t)b * CH * NTOK);
  for (int i4 = t; i4 < CH * NTOK / 4; i4 += 256) {
    float4 v = x4[i4];
    int lf = i4 * 4;
#pragma unroll
    for (int e = 0; e < 4; e++) {
      int idx = lf + e;
      int c = idx / NTOK, n = idx - c * NTOK;
      xsb[c][n] = f2bf(((const float*)&v)[e]);
    }
  }
  __syncthreads();
  int row = t >> 2, sub = t & 3;
  float s = 0.f, s2 = 0.f;
  if (row < NTOK) {
    for (int c = sub; c < CH; c += 4) {
      float v = bf2f(xsb[c][row]);
      s += v;
      s2 += v * v;
    }
  }
  s += __shfl_xor(s, 1);
  s += __shfl_xor(s, 2);
  s2 += __shfl_xor(s2, 1);
  s2 += __shfl_xor(s2, 2);
  if (sub == 0 && row < NTOK) {
    float m = s * (1.f / CH);
    muL[row] = m;
    rsL[row] = rsqrtf(s2 * (1.f / CH) - m * m + 1e-5f);
  }
  __syncthreads();
  ushort* dst = xnW + (size_t)b * NTOK * CH;
  for (int i = t; i < NTOK * 64; i += 256) {
    int n = i >> 6, c0 = (i & 63) * 8;
    float mu = muL[n], rs = rsL[n];
    ushort tmp[8];
#pragma unroll
    for (int j = 0; j < 8; j++) {
      int c = c0 + j;
      tmp[j] = f2bf((bf2f(xsb[c][n]) - mu) * rs * gamma[c] + beta[c]);
    }
    *(uint4*)(dst + (size_t)n * CH + c0) = *(const uint4*)tmp;
  }
}

// ---------------- Kernel 2: QKV GEMM, counted-vmcnt pipeline (order-robust ledger) ----------------
#define QKV_PROLOGUE_STAGE(S)                                                    \
  _Pragma("unroll") for (int i = 0; i < 4; i++)                                  \
      GLOAD_LDS16(xbase + (size_t)(drow + i * 32) * CH + (S) * 64 + gchunk * 8,  \
                  lds + (S) * 8192 + i * 2048 + t * 8);

#define QKV_BLOAD(DST, S)                                                        \
  {                                                                              \
    const ushort* wp_ = wBbase + (size_t)(S) * 8192 + (wn * 4) * 512 + lane * 8; \
    _Pragma("unroll") for (int q_ = 0; q_ < 8; q_++)                             \
        DST[q_] = *(const bf16x8*)(wp_ + (q_ >> 2) * 4096 + (q_ & 3) * 512);     \
  }

#define QKV_STAGE(S, VMC, BCUR, BNXT)                                            \
  {                                                                              \
    asm volatile("s_waitcnt vmcnt(" VMC ")" ::: "memory");                       \
    __builtin_amdgcn_s_barrier();                                                \
    if ((S) + 2 < 8) {                                                           \
      _Pragma("unroll") for (int i = 0; i < 4; i++)                              \
          GLOAD_LDS16(xbase + (size_t)(drow + i * 32) * CH + ((S) + 2) * 64 + gchunk * 8, \
                      lds + (((S) + 2) % 3) * 8192 + i * 2048 + t * 8);          \
    }                                                                            \
    __builtin_amdgcn_sched_barrier(0);                                           \
    if ((S) + 1 < 8) QKV_BLOAD(BNXT, (S) + 1)                                    \
    const ushort* lA_ = lds + ((S) % 3) * 8192;                                  \
    _Pragma("unroll") for (int ks = 0; ks < 2; ks++) {                           \
      bf16x8 afr_[4];                                                            \
      _Pragma("unroll") for (int mt = 0; mt < 4; mt++) {                         \
        int row_ = wm * 64 + mt * 16 + arow;                                     \
        afr_[mt] = *(const bf16x8*)&lA_[row_ * 64 + ((ks * 4 + g) ^ (arow & 7)) * 8]; \
      }                                                                          \
      _Pragma("unroll") for (int mt = 0; mt < 4; mt++)                           \
        _Pragma("unroll") for (int nt = 0; nt < 4; nt++)                         \
            acc[mt][nt] = MFMA16(afr_[mt], BCUR[ks * 4 + nt], acc[mt][nt]);      \
    }                                                                            \
  }

__global__ __launch_bounds__(256, 3) void qkv_gemm(const ushort* __restrict__ xnW,
                                                   const ushort* __restrict__ wqkvB,
                                                   ushort* __restrict__ qW,
                                                   ushort* __restrict__ kW,
                                                   ushort* __restrict__ vW) {
  int bid = blockIdx.x;
  int f = (bid & 7) * 1176 + (bid >> 3);  // bijective XCD swizzle (9408 = 8*1176)
  int mb = f / 12, nb = f - mb * 12;
  int r0 = mb * 128;
  int t = threadIdx.x, lane = t & 63, w = t >> 6;
  int wm = w >> 1, wn = w & 1;

  __shared__ __align__(16) ushort lds[24576];

  const int arow = lane & 15, g = lane >> 4;
  const ushort* wBbase = wqkvB + (size_t)nb * 16 * 4096;
  const ushort* xbase = xnW + (size_t)r0 * CH;

  int drow = t >> 3;
  int slot = t & 7;
  int gchunk = slot ^ (drow & 7);

  f32x4 acc[4][4];
#pragma unroll
  for (int mt = 0; mt < 4; mt++)
#pragma unroll
    for (int nt = 0; nt < 4; nt++) acc[mt][nt] = (f32x4){0.f, 0.f, 0.f, 0.f};

  bf16x8 bA[8], bB[8];
  QKV_PROLOGUE_STAGE(0)
  __builtin_amdgcn_sched_barrier(0);
  QKV_PROLOGUE_STAGE(1)
  QKV_BLOAD(bA, 0)
  // order-robust ledger: S0: gl1(4)+B0(8)=12 | S1..6: gl(S+1)(4)+B(S)(8)=12 | S7: B7(8)=8
  QKV_STAGE(0, "12", bA, bB)
  QKV_STAGE(1, "12", bB, bA)
  QKV_STAGE(2, "12", bA, bB)
  QKV_STAGE(3, "12", bB, bA)
  QKV_STAGE(4, "12", bA, bB)
  QKV_STAGE(5, "12", bB, bA)
  QKV_STAGE(6, "12", bA, bB)
  QKV_STAGE(7, "8", bB, bA)
  __syncthreads();

  ushort(*oL)[136] = (ushort(*)[136])lds;
  int h0 = (nb & 3) * 2;
  int sct = nb >> 2;  // 0=q 1=k 2=v
  float sc = (sct == 0) ? 0.125f : 1.0f;
#pragma unroll
  for (int hh = 0; hh < 2; hh++) {
    if (wm == hh) {
#pragma unroll
      for (int mt = 0; mt < 4; mt++)
#pragma unroll
        for (int nt = 0; nt < 4; nt++)
#pragma unroll
          for (int r = 0; r < 4; r++) {
            int rn = mt * 16 + 4 * g + r;
            oL[rn][wn * 64 + nt * 16 + arow] = f2bf(acc[mt][nt][r] * sc);
          }
    }
    __syncthreads();
    if (sct < 2) {
      ushort* dst = (sct == 0 ? qW : kW);
      for (int i = t; i < 64 * 16; i += 256) {
        int rn = i >> 4, c8 = i & 15;
        int grow = r0 + hh * 64 + rn;
        int b = grow / 49, n = grow - b * 49;
        int h = h0 + (c8 >> 3);
        *(uint4*)(dst + (size_t)(b * 8 + h) * (NTOK * 64) + n * 64 + (c8 & 7) * 8) =
            *(const uint4*)&oL[rn][c8 * 8];
      }
    } else {
      for (int i = t; i < 64 * 128; i += 256) {
        int rn = i & 63, col = i >> 6;
        int grow = r0 + hh * 64 + rn;
        int b = grow / 49, n = grow - b * 49;
        int h = h0 + (col >> 6), d = col & 63;
        vW[(size_t)(b * 8 + h) * 4096 + d * 64 + n] = oL[rn][col];
      }
    }
    __syncthreads();
  }
}

// ---------------- Kernel 3: fused attention + out-proj; x half-0 prefetched at entry ----------------
__global__ __launch_bounds__(512, 3) void attnproj(const ushort* __restrict__ qW,
                                                   const ushort* __restrict__ kW,
                                                   const ushort* __restrict__ vW,
                                                   const float* __restrict__ biasF,
                                                   const ushort* __restrict__ woutF,
                                                   const float* __restrict__ b_out,
                                                   const float* __restrict__ x,
                                                   float* __restrict__ out) {
  int b = blockIdx.x;
  int t = threadIdx.x;
  int lane = t & 63;
  int w = t >> 6;

  __shared__ __align__(16) ushort lds[25480];
  ushort* plb = lds + w * 3136;

  const int c = lane & 15, g = lane >> 4;
  const ushort* qb = qW + (size_t)(b * 8 + w) * NTOK * 64;
  const ushort* kb = kW + (size_t)(b * 8 + w) * NTOK * 64;
  const ushort* vb = vW + (size_t)(b * 8 + w) * 64 * 64;
  const float4* bf = (const float4*)biasF + (size_t)w * 16 * 64;

  // prefetch half-0 residual x (streams under attention+proj compute; 12 VGPR)
  const float4* x40 = (const float4*)(x + (size_t)b * CH * NTOK);
  float4 xp0 = x40[t];
  float4 xp1 = x40[t + 512];
  float4 xp2 = x40[t + 1024];

  f32x4 s[4][4];
#pragma unroll
  for (int mt = 0; mt < 4; mt++)
#pragma unroll
    for (int nt = 0; nt < 4; nt++) s[mt][nt] = (f32x4){0.f, 0.f, 0.f, 0.f};
  __builtin_amdgcn_s_setprio(1);
#pragma unroll
  for (int ks = 0; ks < 2; ks++) {
    bf16x8 kf[4];
#pragma unroll
    for (int nt = 0; nt < 4; nt++)
      kf[nt] = *(const bf16x8*)(kb + (size_t)(nt * 16 + c) * 64 + ks * 32 + g * 8);
#pragma unroll
    for (int mt = 0; mt < 4; mt++) {
      bf16x8 qf = *(const bf16x8*)(qb + (size_t)(mt * 16 + c) * 64 + ks * 32 + g * 8);
#pragma unroll
      for (int nt = 0; nt < 4; nt++) s[mt][nt] = MFMA16(qf, kf[nt], s[mt][nt]);
    }
  }
  __builtin_amdgcn_s_setprio(0);

#pragma unroll
  for (int mt = 0; mt < 4; mt++)
#pragma unroll
    for (int nt = 0; nt < 4; nt++) {
      float4 bb = bf[(mt * 4 + nt) * 64 + lane];
#pragma unroll
      for (int r = 0; r < 4; r++) s[mt][nt][r] += ((const float*)&bb)[r];
    }

#pragma unroll
  for (int mt = 0; mt < 4; mt++)
#pragma unroll
    for (int r = 0; r < 4; r++) {
      float mx = fmaxf(fmaxf(s[mt][0][r], s[mt][1][r]), fmaxf(s[mt][2][r], s[mt][3][r]));
      mx = fmaxf(mx, __shfl_xor(mx, 1));
      mx = fmaxf(mx, __shfl_xor(mx, 2));
      mx = fmaxf(mx, __shfl_xor(mx, 4));
      mx = fmaxf(mx, __shfl_xor(mx, 8));
      float p0 = __expf(s[mt][0][r] - mx);
      float p1 = __expf(s[mt][1][r] - mx);
      float p2 = __expf(s[mt][2][r] - mx);
      float p3 = __expf(s[mt][3][r] - mx);
      float sum = p0 + p1 + p2 + p3;
      sum += __shfl_xor(sum, 1);
      sum += __shfl_xor(sum, 2);
      sum += __shfl_xor(sum, 4);
      sum += __shfl_xor(sum, 8);
      float rinv = 1.f / sum;
      int n = mt * 16 + 4 * g + r;
      if (n < NTOK) {
        int n7 = n & 7;
        int chi = c >> 3, clo = c & 7;
        plb[n * 64 + ((0 + chi) ^ n7) * 8 + clo] = f2bf(p0 * rinv);
        plb[n * 64 + ((2 + chi) ^ n7) * 8 + clo] = f2bf(p1 * rinv);
        plb[n * 64 + ((4 + chi) ^ n7) * 8 + clo] = f2bf(p2 * rinv);
        plb[n * 64 + ((6 + chi) ^ n7) * 8 + clo] = f2bf(p3 * rinv);
      }
    }

  f32x4 o[4][4];
#pragma unroll
  for (int mt = 0; mt < 4; mt++)
#pragma unroll
    for (int nt = 0; nt < 4; nt++) o[mt][nt] = (f32x4){0.f, 0.f, 0.f, 0.f};
  __builtin_amdgcn_s_setprio(1);
#pragma unroll
  for (int ks = 0; ks < 2; ks++) {
    bf16x8 vf[4];
#pragma unroll
    for (int nt = 0; nt < 4; nt++)
      vf[nt] = *(const bf16x8*)(vb + (size_t)(nt * 16 + c) * 64 + ks * 32 + g * 8);
#pragma unroll
    for (int mt = 0; mt < 4; mt++) {
      int row = mt * 16 + c;
      int rr = row < NTOK ? row : 48;
      bf16x8 pf = *(const bf16x8*)&plb[rr * 64 + ((ks * 4 + g) ^ (rr & 7)) * 8];
#pragma unroll
      for (int nt = 0; nt < 4; nt++) o[mt][nt] = MFMA16(pf, vf[nt], o[mt][nt]);
    }
  }
  __builtin_amdgcn_s_setprio(0);

  bf16x8 bcur[4];
#pragma unroll
  for (int nt = 0; nt < 4; nt++)
    bcur[nt] = *(const bf16x8*)(woutF + ((size_t)((w * 4 + nt) * 16 + 0)) * 512 + lane * 8);

  __syncthreads();

  ushort(*aoL)[520] = (ushort(*)[520])lds;
#pragma unroll
  for (int mt = 0; mt < 4; mt++)
#pragma unroll
    for (int nt = 0; nt < 4; nt++)
#pragma unroll
      for (int r = 0; r < 4; r++) {
        int n = mt * 16 + 4 * g + r;
        if (n < NTOK) aoL[n][w * 64 + nt * 16 + c] = f2bf(o[mt][nt][r]);
      }
  __syncthreads();

  f32x4 pacc[4][4];
#pragma unroll
  for (int mt = 0; mt < 4; mt++)
#pragma unroll
    for (int nt = 0; nt < 4; nt++) pacc[mt][nt] = (f32x4){0.f, 0.f, 0.f, 0.f};
#pragma unroll
  for (int step = 0; step < 16; step++) {
    bf16x8 bnxt[4];
    if (step < 15) {
#pragma unroll
      for (int nt = 0; nt < 4; nt++)
        bnxt[nt] = *(const bf16x8*)(woutF + ((size_t)((w * 4 + nt) * 16 + step + 1)) * 512 + lane * 8);
    }
    bf16x8 afr[4];
#pragma unroll
    for (int mt = 0; mt < 4; mt++) {
      int row = mt * 16 + c;
      int rr = row < NTOK ? row : 48;
      afr[mt] = *(const bf16x8*)&aoL[rr][step * 32 + g * 8];
    }
    __builtin_amdgcn_s_setprio(1);
#pragma unroll
    for (int mt = 0; mt < 4; mt++)
#pragma unroll
      for (int nt = 0; nt < 4; nt++) pacc[mt][nt] = MFMA16(afr[mt], bcur[nt], pacc[mt][nt]);
    __builtin_amdgcn_s_setprio(0);
#pragma unroll
    for (int nt = 0; nt < 4; nt++) bcur[nt] = bnxt[nt];
  }

  float(*oL)[260] = (float(*)[260])lds;
  // ---- half 0: uses prefetched xp0..xp2 for the first 3 strides ----
  __syncthreads();
  if ((w >> 2) == 0) {
    int wl = w & 3;
#pragma unroll
    for (int mt = 0; mt < 4; mt++)
#pragma unroll
      for (int nt = 0; nt < 4; nt++)
#pragma unroll
        for (int r = 0; r < 4; r++) {
          int rn = mt * 16 + 4 * g + r;
          if (rn < NTOK) oL[rn][wl * 64 + nt * 16 + c] = pacc[mt][nt][r];
        }
  }
  __syncthreads();
  {
    float4* o4 = (float4*)(out + (size_t)b * CH * NTOK);
    const float* bo = b_out;
#pragma unroll
    for (int k = 0; k < 7; k++) {
      int i = t + k * 512;
      if (k < 6 || i < 3136) {
        float4 xv = (k == 0) ? xp0 : (k == 1) ? xp1 : (k == 2) ? xp2 : x40[i];
        float4 ov;
        int lf = i * 4;
#pragma unroll
        for (int e = 0; e < 4; e++) {
          int cl = (lf + e) / NTOK, n = (lf + e) - cl * NTOK;
          ((float*)&ov)[e] = oL[n][cl] + bo[cl] + ((const float*)&xv)[e];
        }
        o4[i] = ov;
      }
    }
  }
  // ---- half 1 ----
  __syncthreads();
  if ((w >> 2) == 1) {
    int wl = w & 3;
#pragma unroll
    for (int mt = 0; mt < 4; mt++)
#pragma unroll
      for (int nt = 0; nt < 4; nt++)
#pragma unroll
        for (int r = 0; r < 4; r++) {
          int rn = mt * 16 + 4 * g + r;
          if (rn < NTOK) oL[rn][wl * 64 + nt * 16 + c] = pacc[mt][nt][r];
        }
  }
  __syncthreads();
  {
    const float4* x41 = (const float4*)(x + ((size_t)b * CH + 256) * NTOK);
    float4* o4 = (float4*)(out + ((size_t)b * CH + 256) * NTOK);
    const float* bo = b_out + 256;
    for (int i = t; i < 3136; i += 512) {
      float4 xv = x41[i];
      float4 ov;
      int lf = i * 4;
#pragma unroll
      for (int e = 0; e < 4; e++) {
        int cl = (lf + e) / NTOK, n = (lf + e) - cl * NTOK;
        ((float*)&ov)[e] = oL[n][cl] + bo[cl] + ((const float*)&xv)[e];
      }
      o4[i] = ov;
    }
  }
}

extern "C" void kernel_launch(void* const* d_in, const int* in_sizes, int n_in,
                              void* d_out, int out_size, void* d_ws, size_t ws_size,
                              hipStream_t stream) {
  const float* x = (const float*)d_in[0];
  const float* gamma = (const float*)d_in[1];
  const float* beta = (const float*)d_in[2];
  const float* w_qkv = (const float*)d_in[3];
  const float* rel = (const float*)d_in[4];
  const float* w_out = (const float*)d_in[5];
  const float* b_out = (const float*)d_in[6];
  float* out = (float*)d_out;

  char* ws = (char*)d_ws;
  size_t off = 0;
  ushort* wqkvB = (ushort*)(ws + off); off += (size_t)12 * 16 * 4096 * 2;
  ushort* woutF = (ushort*)(ws + off); off += (size_t)512 * 512 * 2;
  float* biasF = (float*)(ws + off);   off += (size_t)NHEAD * 16 * 64 * 4 * 4;  // 128 KB
  ushort* qW = (ushort*)(ws + off);    off += ((size_t)BATCH * 8 * NTOK * 64 + 1024) * 2;
  ushort* kW = (ushort*)(ws + off);    off += ((size_t)BATCH * 8 * NTOK * 64 + 1024) * 2;
  ushort* vW = (ushort*)(ws + off);    off += (size_t)BATCH * 8 * 64 * 64 * 2;
  ushort* xnW = (ushort*)(ws + off);   off += (size_t)BATCH * NTOK * CH * 2;
  (void)ws_size;

  prep_kernel<<<1024, 256, 0, stream>>>(w_qkv, w_out, rel, wqkvB, woutF, biasF);
  ln_kernel<<<BATCH, 256, 0, stream>>>(x, gamma, beta, xnW);
  qkv_gemm<<<784 * 12, 256, 0, stream>>>(xnW, wqkvB, qW, kW, vW);
  attnproj<<<BATCH, 512, 0, stream>>>(qW, kW, vW, biasF, woutF, b_out, x, out);
}